// Round 1
// 21815.034 us; speedup vs baseline: 1.5568x; 1.5568x over previous
//
#include <hip/hip_runtime.h>
#include <math.h>

// GPT-2 small forward: L=12 N=12 D=768 F=3072 V=50257 B=4 T=1024 HD=64
// GEMMs moved to bf16 MFMA with 2-term split (Ah*Bh + Ah*Bl + Al*Bh) for
// near-fp32 accuracy at matrix-core rate. m97-style 128x128 tile, BK=32,
// global_load_lds staging. Fallback to old fp32 path if workspace too small.
namespace {
constexpr int LAYERS = 12;
constexpr int NHEAD  = 12;
constexpr int DMODEL = 768;
constexpr int DFF    = 3072;
constexpr int VOCAB  = 50257;
constexpr int BATCH  = 4;
constexpr int SEQ    = 1024;
constexpr int HDIM   = 64;
constexpr int ROWS   = BATCH * SEQ;   // 4096
constexpr int LMCHUNK = 8192;         // lm_head N-chunk (rows of wte)

typedef unsigned short u16;
typedef unsigned int   u32;
typedef short short8 __attribute__((ext_vector_type(8)));   // 8 bf16 in 4 VGPR
typedef float f32x4  __attribute__((ext_vector_type(4)));

__device__ __forceinline__ u16 f2bf(float f) {            // RNE fp32->bf16
    u32 u = __builtin_bit_cast(u32, f);
    u += 0x7FFFu + ((u >> 16) & 1u);
    return (u16)(u >> 16);
}
__device__ __forceinline__ float bf2f(u16 b) {
    u32 u = ((u32)b) << 16;
    return __builtin_bit_cast(float, u);
}
__device__ __forceinline__ void splitst(float v, u16* ph, u16* pl) {
    u16 h = f2bf(v);
    *ph = h;
    *pl = f2bf(v - bf2f(h));   // exact residual in fp32
}
__device__ __forceinline__ void gload16(const void* g, void* l) {
    __builtin_amdgcn_global_load_lds(
        (const __attribute__((address_space(1))) void*)g,
        (__attribute__((address_space(3))) void*)l, 16, 0, 0);
}

// ---------------- embedding: x = wte[tok] + wpe[t] ----------------
__global__ void k_embed(const int* __restrict__ tok, const float* __restrict__ wte,
                        const float* __restrict__ wpe, float* __restrict__ x) {
    int row = blockIdx.x;
    int t   = row & (SEQ - 1);
    int tk  = tok[row];
    const float* a = wte + (size_t)tk * DMODEL;
    const float* p = wpe + (size_t)t * DMODEL;
    float* o = x + (size_t)row * DMODEL;
    for (int d = threadIdx.x; d < DMODEL; d += blockDim.x)
        o[d] = a[d] + p[d];
}

// ---------------- layernorm (fp32 out, fallback path) ----------------
__global__ void k_ln(const float* __restrict__ in, float* __restrict__ out,
                     const float* __restrict__ g, const float* __restrict__ bb) {
    int row = blockIdx.x;
    const float* xr = in + (size_t)row * DMODEL;
    float* yr = out + (size_t)row * DMODEL;
    int i0 = threadIdx.x;
    float v0 = xr[i0], v1 = xr[i0 + 256], v2 = xr[i0 + 512];
    float s  = v0 + v1 + v2;
    float ss = v0 * v0 + v1 * v1 + v2 * v2;
#pragma unroll
    for (int o = 32; o > 0; o >>= 1) {
        s  += __shfl_down(s, o, 64);
        ss += __shfl_down(ss, o, 64);
    }
    __shared__ float sh[8];
    int lane = threadIdx.x & 63, w = threadIdx.x >> 6;
    if (lane == 0) { sh[w] = s; sh[w + 4] = ss; }
    __syncthreads();
    s  = sh[0] + sh[1] + sh[2] + sh[3];
    ss = sh[4] + sh[5] + sh[6] + sh[7];
    float mean = s * (1.0f / DMODEL);
    float var  = ss * (1.0f / DMODEL) - mean * mean;
    float rstd = rsqrtf(var + 1e-5f);
    yr[i0]       = (v0 - mean) * rstd * g[i0]       + bb[i0];
    yr[i0 + 256] = (v1 - mean) * rstd * g[i0 + 256] + bb[i0 + 256];
    yr[i0 + 512] = (v2 - mean) * rstd * g[i0 + 512] + bb[i0 + 512];
}

// ---------------- layernorm -> split bf16 hi/lo ----------------
__global__ void k_ln_split(const float* __restrict__ in, u16* __restrict__ oh,
                           u16* __restrict__ ol, const float* __restrict__ g,
                           const float* __restrict__ bb) {
    int row = blockIdx.x;
    const float* xr = in + (size_t)row * DMODEL;
    int i0 = threadIdx.x;
    float v0 = xr[i0], v1 = xr[i0 + 256], v2 = xr[i0 + 512];
    float s  = v0 + v1 + v2;
    float ss = v0 * v0 + v1 * v1 + v2 * v2;
#pragma unroll
    for (int o = 32; o > 0; o >>= 1) {
        s  += __shfl_down(s, o, 64);
        ss += __shfl_down(ss, o, 64);
    }
    __shared__ float sh[8];
    int lane = threadIdx.x & 63, w = threadIdx.x >> 6;
    if (lane == 0) { sh[w] = s; sh[w + 4] = ss; }
    __syncthreads();
    s  = sh[0] + sh[1] + sh[2] + sh[3];
    ss = sh[4] + sh[5] + sh[6] + sh[7];
    float mean = s * (1.0f / DMODEL);
    float var  = ss * (1.0f / DMODEL) - mean * mean;
    float rstd = rsqrtf(var + 1e-5f);
    size_t base = (size_t)row * DMODEL;
    float y0 = (v0 - mean) * rstd * g[i0]       + bb[i0];
    float y1 = (v1 - mean) * rstd * g[i0 + 256] + bb[i0 + 256];
    float y2 = (v2 - mean) * rstd * g[i0 + 512] + bb[i0 + 512];
    splitst(y0, oh + base + i0,       ol + base + i0);
    splitst(y1, oh + base + i0 + 256, ol + base + i0 + 256);
    splitst(y2, oh + base + i0 + 512, ol + base + i0 + 512);
}

// ---------------- old fp32 GEMM (fallback path only) ----------------
template <bool TRB, bool GELU_ACT, bool HASRES>
__global__ void k_gemm(const float* __restrict__ A, const float* __restrict__ Bm,
                       const float* __restrict__ bias, const float* __restrict__ res,
                       float* __restrict__ C, int M, int Nn, int K) {
    __shared__ __align__(16) float As[16][68];
    __shared__ __align__(16) float Bs[16][68];
    const int tid = threadIdx.x;
    const int m0 = blockIdx.y * 64, n0 = blockIdx.x * 64;
    const int tx = tid & 15, ty = tid >> 4;
    const int am = tid >> 2, ak = (tid & 3) << 2;
    const int bn_nn = tid & 63, bk0 = tid >> 6;
    const int bn_nt = tid >> 2, bk_nt = (tid & 3) << 2;
    float acc[4][4] = {};
    for (int k0 = 0; k0 < K; k0 += 16) {
        __syncthreads();
        {
            const float4 av = *(const float4*)(A + (size_t)(m0 + am) * K + k0 + ak);
            As[ak + 0][am] = av.x; As[ak + 1][am] = av.y;
            As[ak + 2][am] = av.z; As[ak + 3][am] = av.w;
        }
        if (TRB) {
            float4 bv = make_float4(0.f, 0.f, 0.f, 0.f);
            if (n0 + bn_nt < Nn)
                bv = *(const float4*)(Bm + (size_t)(n0 + bn_nt) * K + k0 + bk_nt);
            Bs[bk_nt + 0][bn_nt] = bv.x; Bs[bk_nt + 1][bn_nt] = bv.y;
            Bs[bk_nt + 2][bn_nt] = bv.z; Bs[bk_nt + 3][bn_nt] = bv.w;
        } else {
            const bool ok = (n0 + bn_nn) < Nn;
#pragma unroll
            for (int kk = bk0; kk < 16; kk += 4)
                Bs[kk][bn_nn] = ok ? Bm[(size_t)(k0 + kk) * Nn + n0 + bn_nn] : 0.f;
        }
        __syncthreads();
#pragma unroll
        for (int k = 0; k < 16; k++) {
            const float4 a4 = *(const float4*)&As[k][ty << 2];
            const float4 b4 = *(const float4*)&Bs[k][tx << 2];
            const float ar[4] = {a4.x, a4.y, a4.z, a4.w};
            const float br[4] = {b4.x, b4.y, b4.z, b4.w};
#pragma unroll
            for (int i = 0; i < 4; i++)
#pragma unroll
                for (int j = 0; j < 4; j++)
                    acc[i][j] = fmaf(ar[i], br[j], acc[i][j]);
        }
    }
#pragma unroll
    for (int i = 0; i < 4; i++) {
        const int m = m0 + (ty << 2) + i;
#pragma unroll
        for (int j = 0; j < 4; j++) {
            const int n = n0 + (tx << 2) + j;
            if (n < Nn) {
                float v = acc[i][j];
                if (bias) v += bias[n];
                if (GELU_ACT) v = 0.5f * v * (1.0f + erff(v * 0.7071067811865475f));
                if (HASRES) v += res[(size_t)m * Nn + n];
                C[(size_t)m * Nn + n] = v;
            }
        }
    }
}

// ---------------- block reductions ----------------
__device__ __forceinline__ float blk_max(float v) {
    __shared__ float sh[4];
#pragma unroll
    for (int o = 32; o > 0; o >>= 1) v = fmaxf(v, __shfl_down(v, o, 64));
    int lane = threadIdx.x & 63, w = threadIdx.x >> 6;
    __syncthreads();
    if (lane == 0) sh[w] = v;
    __syncthreads();
    return fmaxf(fmaxf(sh[0], sh[1]), fmaxf(sh[2], sh[3]));
}
__device__ __forceinline__ float blk_sum(float v) {
    __shared__ float sh[4];
#pragma unroll
    for (int o = 32; o > 0; o >>= 1) v += __shfl_down(v, o, 64);
    int lane = threadIdx.x & 63, w = threadIdx.x >> 6;
    __syncthreads();
    if (lane == 0) sh[w] = v;
    __syncthreads();
    return sh[0] + sh[1] + sh[2] + sh[3];
}

// ---------------- attention: one block per (t, head, batch) ----------------
// output: either fp32 (of) or split bf16 (oh/ol) when oh != nullptr
__global__ void k_attn(const float* __restrict__ qkv, float* __restrict__ of,
                       u16* __restrict__ oh, u16* __restrict__ ol) {
    const int t = blockIdx.x, h = blockIdx.y, b = blockIdx.z;
    __shared__ __align__(16) float q[HDIM];
    __shared__ float sc[SEQ];
    const float* qp = qkv + ((size_t)(b * SEQ + t)) * (3 * DMODEL) + h * HDIM;
    if (threadIdx.x < HDIM) q[threadIdx.x] = qp[threadIdx.x];
    __syncthreads();
    float lmax = -1e30f;
    for (int s = threadIdx.x; s <= t; s += 256) {
        const float* kp = qkv + ((size_t)(b * SEQ + s)) * (3 * DMODEL) + DMODEL + h * HDIM;
        float acc = 0.f;
#pragma unroll
        for (int d = 0; d < HDIM; d += 4) {
            const float4 kv = *(const float4*)(kp + d);
            acc += q[d] * kv.x + q[d + 1] * kv.y + q[d + 2] * kv.z + q[d + 3] * kv.w;
        }
        acc *= 0.125f;
        sc[s] = acc;
        lmax = fmaxf(lmax, acc);
    }
    const float m = blk_max(lmax);
    float lsum = 0.f;
    for (int s = threadIdx.x; s <= t; s += 256) {
        const float e = __expf(sc[s] - m);
        sc[s] = e;
        lsum += e;
    }
    const float denom = blk_sum(lsum);
    const float inv = 1.0f / denom;
    const int d = threadIdx.x & 63, grp = threadIdx.x >> 6;
    float acc = 0.f;
    for (int s = grp; s <= t; s += 4) {
        const float* vp = qkv + ((size_t)(b * SEQ + s)) * (3 * DMODEL) + 2 * DMODEL + h * HDIM;
        acc += sc[s] * vp[d];
    }
    __shared__ float ored[4][HDIM];
    ored[grp][d] = acc;
    __syncthreads();
    if (threadIdx.x < HDIM) {
        const float r = (ored[0][d] + ored[1][d] + ored[2][d] + ored[3][d]) * inv;
        const size_t o = ((size_t)(b * SEQ + t)) * DMODEL + h * HDIM + d;
        if (oh) {
            u16 hb = f2bf(r);
            oh[o] = hb;
            ol[o] = f2bf(r - bf2f(hb));
        } else {
            of[o] = r;
        }
    }
}

// ---------------- weight convert: fp32 W[K,N] -> bf16 hi/lo [N,K] ----------------
// grid (N/32, K/32), block (32,8); K,N multiples of 32
__global__ void k_wconv_t(const float* __restrict__ W, u16* __restrict__ Wh,
                          u16* __restrict__ Wl, int K, int N) {
    __shared__ float t[32][33];
    const int nb = blockIdx.x * 32, kb = blockIdx.y * 32;
    const int tx = threadIdx.x, ty = threadIdx.y;
#pragma unroll
    for (int j = 0; j < 32; j += 8)
        t[ty + j][tx] = W[(size_t)(kb + ty + j) * N + nb + tx];
    __syncthreads();
#pragma unroll
    for (int j = 0; j < 32; j += 8) {
        float v = t[tx][ty + j];             // = W[kb+tx][nb+ty+j]
        size_t o = (size_t)(nb + ty + j) * K + kb + tx;
        splitst(v, Wh + o, Wl + o);
    }
}

// ---------------- wte chunk convert (already [N,K]); pad rows with zeros ----------------
__global__ void k_wconv_rows(const float* __restrict__ W, u16* __restrict__ Wh,
                             u16* __restrict__ Wl, int r0, int nvalid) {
    const int r = blockIdx.x;
    const size_t o = (size_t)r * DMODEL;
    if (r < nvalid) {
        const float* src = W + (size_t)(r0 + r) * DMODEL;
        for (int d = threadIdx.x; d < DMODEL; d += 256)
            splitst(src[d], Wh + o + d, Wl + o + d);
    } else {
        for (int d = threadIdx.x; d < DMODEL; d += 256) { Wh[o + d] = 0; Wl[o + d] = 0; }
    }
}

// ---------------- split-bf16 MFMA GEMM ----------------
// A: hi/lo bf16 [M,K] row-major.  B: hi/lo bf16 [N,K] row-major (pre-transposed).
// C = A@B^T_math (+bias)(+gelu)(+res). 128x128 tile, BK=32, 256 thr / 4 waves.
// EPI: 0 = bias -> fp32 ; 1 = bias+res -> fp32 ; 2 = bias+gelu -> split bf16 ;
//      3 = plain -> fp32 (lm_head, col guard nvalid)
template <int EPI>
__global__ __launch_bounds__(256) void k_mm(
        const u16* __restrict__ Ah, const u16* __restrict__ Al,
        const u16* __restrict__ Bh, const u16* __restrict__ Bl,
        const float* __restrict__ bias, const float* __restrict__ res,
        float* __restrict__ Cf, u16* __restrict__ Chi, u16* __restrict__ Clo,
        int K, int ldc, int nvalid) {
    __shared__ u16 lds[4 * 4096];    // Ah | Al | Bh | Bl tiles, each [128][32]
    const int tid = threadIdx.x, wid = tid >> 6, lane = tid & 63;
    const int m0 = blockIdx.y * 128, n0 = blockIdx.x * 128;
    // staging: wave w fills 16-row groups j=2w, 2w+1 of each buffer
    const int ldr = lane >> 2, lkc = (lane & 3) * 8;
    const size_t aoff = (size_t)(m0 + ldr) * K + lkc;
    const size_t boff = (size_t)(n0 + ldr) * K + lkc;
    const int j0 = wid * 2, j1 = j0 + 1;
    u16* LAh = lds;         u16* LAl = lds + 4096;
    u16* LBh = lds + 8192;  u16* LBl = lds + 12288;
    // fragment addressing
    const int fr = lane & 15, fq = lane >> 4;
    const int wr = (wid >> 1) * 64, wc = (wid & 1) * 64;
    f32x4 acc[4][4] = {};
    for (int k0 = 0; k0 < K; k0 += 32) {
        __syncthreads();
        {
            const size_t a0 = aoff + (size_t)(16 * j0) * K + k0;
            const size_t a1 = aoff + (size_t)(16 * j1) * K + k0;
            const size_t b0 = boff + (size_t)(16 * j0) * K + k0;
            const size_t b1 = boff + (size_t)(16 * j1) * K + k0;
            gload16(Ah + a0, LAh + j0 * 512);
            gload16(Ah + a1, LAh + j1 * 512);
            gload16(Al + a0, LAl + j0 * 512);
            gload16(Al + a1, LAl + j1 * 512);
            gload16(Bh + b0, LBh + j0 * 512);
            gload16(Bh + b1, LBh + j1 * 512);
            gload16(Bl + b0, LBl + j0 * 512);
            gload16(Bl + b1, LBl + j1 * 512);
        }
        __syncthreads();   // compiler drains vmcnt before barrier -> tiles ready
        short8 vah[4], valo[4], vbh[4], vblo[4];
#pragma unroll
        for (int i = 0; i < 4; i++) {
            const int ra = (wr + i * 16 + fr) * 32 + fq * 8;
            vah[i]  = *(const short8*)(LAh + ra);
            valo[i] = *(const short8*)(LAl + ra);
            const int rb = (wc + i * 16 + fr) * 32 + fq * 8;
            vbh[i]  = *(const short8*)(LBh + rb);
            vblo[i] = *(const short8*)(LBl + rb);
        }
#pragma unroll
        for (int i = 0; i < 4; i++)
#pragma unroll
            for (int j = 0; j < 4; j++) {
                acc[i][j] = __builtin_amdgcn_mfma_f32_16x16x32_bf16(vah[i],  vbh[j],  acc[i][j], 0, 0, 0);
                acc[i][j] = __builtin_amdgcn_mfma_f32_16x16x32_bf16(vah[i],  vblo[j], acc[i][j], 0, 0, 0);
                acc[i][j] = __builtin_amdgcn_mfma_f32_16x16x32_bf16(valo[i], vbh[j],  acc[i][j], 0, 0, 0);
            }
    }
    // epilogue: C/D layout col=lane&15, row=(lane>>4)*4+reg  [verified m89]
#pragma unroll
    for (int j = 0; j < 4; j++) {
        const int col = n0 + wc + j * 16 + fr;
        if (col >= nvalid) continue;
        float bj = 0.f;
        if (EPI != 3) bj = bias[col];
#pragma unroll
        for (int i = 0; i < 4; i++) {
#pragma unroll
            for (int r = 0; r < 4; r++) {
                const int row = m0 + wr + i * 16 + fq * 4 + r;
                float v = acc[i][j][r] + bj;
                if (EPI == 2) v = 0.5f * v * (1.0f + erff(v * 0.7071067811865475f));
                const size_t o = (size_t)row * ldc + col;
                if (EPI == 1) v += res[o];
                if (EPI == 2) splitst(v, Chi + o, Clo + o);
                else          Cf[o] = v;
            }
        }
    }
}
} // namespace

extern "C" void kernel_launch(void* const* d_in, const int* in_sizes, int n_in,
                              void* d_out, int out_size, void* d_ws, size_t ws_size,
                              hipStream_t stream) {
    const int*   tok  = (const int*)d_in[0];
    const float* wte  = (const float*)d_in[1];
    const float* wpe  = (const float*)d_in[2];
    const float* ln1g = (const float*)d_in[3];
    const float* ln1b = (const float*)d_in[4];
    const float* aw   = (const float*)d_in[5];
    const float* ab   = (const float*)d_in[6];
    const float* pw   = (const float*)d_in[7];
    const float* pb   = (const float*)d_in[8];
    const float* ln2g = (const float*)d_in[9];
    const float* ln2b = (const float*)d_in[10];
    const float* fw   = (const float*)d_in[11];
    const float* fb   = (const float*)d_in[12];
    const float* mw   = (const float*)d_in[13];
    const float* mb   = (const float*)d_in[14];
    const float* lnfg = (const float*)d_in[15];
    const float* lnfb = (const float*)d_in[16];
    float* out = (float*)d_out;

    const dim3 blk(256);

    // ---- workspace need for the MFMA path (~151 MB) ----
    const size_t SZ_X   = (size_t)ROWS * DMODEL * 4;       // fp32 residual
    const size_t SZ_QKV = (size_t)ROWS * 3 * DMODEL * 4;   // fp32 qkv
    const size_t SZ_H   = (size_t)ROWS * DMODEL * 2;       // one bf16 plane [4096,768]
    const size_t SZ_MH  = (size_t)ROWS * DFF * 2;          // one bf16 plane [4096,3072]
    const size_t SZ_WB  = (size_t)LMCHUNK * DMODEL * 2;    // one bf16 plane [8192,768]
    const size_t need = SZ_X + SZ_QKV + 2 * SZ_H + 2 * SZ_H + 2 * SZ_MH + 2 * SZ_WB;

    if (ws_size >= need) {
        // ---------------- MFMA split-bf16 path ----------------
        char* p = (char*)d_ws;
        float* x   = (float*)p;  p += SZ_X;
        float* qkv = (float*)p;  p += SZ_QKV;
        u16* hh  = (u16*)p;  p += SZ_H;
        u16* hl  = (u16*)p;  p += SZ_H;
        u16* aoh = (u16*)p;  p += SZ_H;
        u16* aol = (u16*)p;  p += SZ_H;
        u16* mhh = (u16*)p;  p += SZ_MH;
        u16* mhl = (u16*)p;  p += SZ_MH;
        u16* wbh = (u16*)p;  p += SZ_WB;
        u16* wbl = (u16*)p;  p += SZ_WB;

        k_embed<<<ROWS, blk, 0, stream>>>(tok, wte, wpe, x);
        for (int l = 0; l < LAYERS; l++) {
            k_ln_split<<<ROWS, blk, 0, stream>>>(x, hh, hl, ln1g + l * DMODEL, ln1b + l * DMODEL);
            k_wconv_t<<<dim3(3 * DMODEL / 32, DMODEL / 32), dim3(32, 8), 0, stream>>>(
                aw + (size_t)l * DMODEL * 3 * DMODEL, wbh, wbl, DMODEL, 3 * DMODEL);
            k_mm<0><<<dim3(3 * DMODEL / 128, ROWS / 128), blk, 0, stream>>>(
                hh, hl, wbh, wbl, ab + l * 3 * DMODEL, nullptr,
                qkv, nullptr, nullptr, DMODEL, 3 * DMODEL, 3 * DMODEL);
            k_attn<<<dim3(SEQ, NHEAD, BATCH), blk, 0, stream>>>(qkv, nullptr, aoh, aol);
            k_wconv_t<<<dim3(DMODEL / 32, DMODEL / 32), dim3(32, 8), 0, stream>>>(
                pw + (size_t)l * DMODEL * DMODEL, wbh, wbl, DMODEL, DMODEL);
            k_mm<1><<<dim3(DMODEL / 128, ROWS / 128), blk, 0, stream>>>(
                aoh, aol, wbh, wbl, pb + l * DMODEL, x,
                x, nullptr, nullptr, DMODEL, DMODEL, DMODEL);
            k_ln_split<<<ROWS, blk, 0, stream>>>(x, hh, hl, ln2g + l * DMODEL, ln2b + l * DMODEL);
            k_wconv_t<<<dim3(DFF / 32, DMODEL / 32), dim3(32, 8), 0, stream>>>(
                fw + (size_t)l * DMODEL * DFF, wbh, wbl, DMODEL, DFF);
            k_mm<2><<<dim3(DFF / 128, ROWS / 128), blk, 0, stream>>>(
                hh, hl, wbh, wbl, fb + l * DFF, nullptr,
                nullptr, mhh, mhl, DMODEL, DFF, DFF);
            k_wconv_t<<<dim3(DMODEL / 32, DFF / 32), dim3(32, 8), 0, stream>>>(
                mw + (size_t)l * DFF * DMODEL, wbh, wbl, DFF, DMODEL);
            k_mm<1><<<dim3(DMODEL / 128, ROWS / 128), blk, 0, stream>>>(
                mhh, mhl, wbh, wbl, mb + l * DMODEL, x,
                x, nullptr, nullptr, DFF, DMODEL, DMODEL);
        }
        k_ln_split<<<ROWS, blk, 0, stream>>>(x, hh, hl, lnfg, lnfb);
        // lm_head in N-chunks: convert wte chunk -> split bf16, then MFMA GEMM
        for (int c0 = 0; c0 < VOCAB; c0 += LMCHUNK) {
            const int rows = (VOCAB - c0 < LMCHUNK) ? (VOCAB - c0) : LMCHUNK;
            const int pad  = (rows + 127) & ~127;
            k_wconv_rows<<<pad, blk, 0, stream>>>(wte, wbh, wbl, c0, rows);
            k_mm<3><<<dim3(pad / 128, ROWS / 128), blk, 0, stream>>>(
                hh, hl, wbh, wbl, nullptr, nullptr,
                out + c0, nullptr, nullptr, DMODEL, VOCAB, rows);
        }
    } else {
        // ---------------- fallback: previous verified fp32 path ----------------
        float* ws  = (float*)d_ws;
        float* x   = ws;
        float* h   = x   + (size_t)ROWS * DMODEL;
        float* qkv = h   + (size_t)ROWS * DMODEL;
        float* ao  = qkv + (size_t)ROWS * 3 * DMODEL;
        float* mh  = ao  + (size_t)ROWS * DMODEL;

        k_embed<<<ROWS, blk, 0, stream>>>(tok, wte, wpe, x);
        for (int l = 0; l < LAYERS; l++) {
            k_ln<<<ROWS, blk, 0, stream>>>(x, h, ln1g + l * DMODEL, ln1b + l * DMODEL);
            k_gemm<false, false, false><<<dim3(3 * DMODEL / 64, ROWS / 64), blk, 0, stream>>>(
                h, aw + (size_t)l * DMODEL * 3 * DMODEL, ab + l * 3 * DMODEL, nullptr,
                qkv, ROWS, 3 * DMODEL, DMODEL);
            k_attn<<<dim3(SEQ, NHEAD, BATCH), blk, 0, stream>>>(qkv, ao, nullptr, nullptr);
            k_gemm<false, false, true><<<dim3(DMODEL / 64, ROWS / 64), blk, 0, stream>>>(
                ao, pw + (size_t)l * DMODEL * DMODEL, pb + l * DMODEL, x,
                x, ROWS, DMODEL, DMODEL);
            k_ln<<<ROWS, blk, 0, stream>>>(x, h, ln2g + l * DMODEL, ln2b + l * DMODEL);
            k_gemm<false, true, false><<<dim3(DFF / 64, ROWS / 64), blk, 0, stream>>>(
                h, fw + (size_t)l * DMODEL * DFF, fb + l * DFF, nullptr,
                mh, ROWS, DFF, DMODEL);
            k_gemm<false, false, true><<<dim3(DMODEL / 64, ROWS / 64), blk, 0, stream>>>(
                mh, mw + (size_t)l * DFF * DMODEL, mb + l * DMODEL, x,
                x, ROWS, DMODEL, DFF);
        }
        k_ln<<<ROWS, blk, 0, stream>>>(x, h, lnfg, lnfb);
        k_gemm<true, false, false><<<dim3((VOCAB + 63) / 64, ROWS / 64), blk, 0, stream>>>(
            h, wte, nullptr, nullptr, out, ROWS, VOCAB, DMODEL);
    }
}